// Round 10
// baseline (177.372 us; speedup 1.0000x reference)
//
#include <hip/hip_runtime.h>

// Problem constants (from reference; all fp32 I/O)
#define NVIEW 5
#define NB    128000          // NBINS = 80*80*20
#define CF    32
#define HID   256
#define KA    96              // padded K for the MLP GEMM
#define IMG_HW 262144         // 512*512
#define FT_HW  16384          // 128*128

typedef __attribute__((ext_vector_type(8))) short short8;     // 8 bf16 (4 VGPRs)
typedef __attribute__((ext_vector_type(4))) float f32x4;      // MFMA accumulator
typedef __attribute__((ext_vector_type(2))) float f32x2;      // packed fp32 (v_pk_*)

__device__ __forceinline__ unsigned int f2bf(float f) {
    unsigned int u = __float_as_uint(f);
    return (u + 0x7fffu + ((u >> 16) & 1u)) >> 16;   // RTNE, low 16 bits
}
__device__ __forceinline__ unsigned int pk(float a, float b) {
    return f2bf(a) | (f2bf(b) << 16);
}
__device__ __forceinline__ float b2f_lo(unsigned int u) { return __uint_as_float(u << 16); }
__device__ __forceinline__ float b2f_hi(unsigned int u) { return __uint_as_float(u & 0xffff0000u); }

// A-row layout, QUARTER-ROW ownership (96 shorts per row = bin 2n+b, built by
// 4 threads q=0..3; thread q owns shorts [24q, 24q+24) = granules 3q..3q+2):
//  q0: mi(3) vi(3) mf ch0..7 (8) vf ch0..7 (8) pad(2)
//  q1: mf ch8..15 (8)  vf ch8..15 (8)  pad(8)
//  q2: mf ch16..23 (8) vf ch16..23 (8) pad(8)
//  q3: mf ch24..31 (8) vf ch24..31 (8) pts(3) pad(5)
// W1 input order i: 0-2 pts | 3-5 img_mean | 6-37 feat_mean | 38-40 img_var
// | 41-72 feat_var.  mapk: A-row k -> i, -1 = zero pad.
__device__ __forceinline__ int mapk(int k) {
    if (k < 3)  return k + 3;      // img mean
    if (k < 6)  return k + 35;     // img var (38..40)
    if (k < 14) return k;          // feat mean 0..7  (6..13)
    if (k < 22) return k + 27;     // feat var 0..7   (41..48)
    if (k < 24) return -1;
    if (k < 32) return k - 10;     // feat mean 8..15 (14..21)
    if (k < 40) return k + 17;     // feat var 8..15  (49..56)
    if (k < 48) return -1;
    if (k < 56) return k - 26;     // feat mean 16..23 (22..29)
    if (k < 64) return k + 1;      // feat var 16..23  (57..64)
    if (k < 72) return -1;
    if (k < 80) return k - 42;     // feat mean 24..31 (30..37)
    if (k < 88) return k - 15;     // feat var 24..31  (65..72)
    if (k < 91) return k - 88;     // pts
    return -1;
}

// ---------------------------------------------------------------------------
// Kernel 1: ALL preprocessing in one launch (blockIdx-range split).
//  [0,1280):    repack imgs (4 px/thread) -> [V][512][512][8] uint8 fixed-pt
//  [1280,2560): repack feats -> [V][128][128][2][32] bf16 (LDS tile, float4 loads)
//  [2560,2608): build W1 B-fragment image + b1|W2|b2 staging
// NUMERICS LESSON (r6/r7): harness re-poisons inputs; feats can carry
// magnitudes far outside N(0,1) (f16 storage -> 3.5e-2 error / inf risk).
// bf16 keeps f32's exponent range -> always safe.
// ---------------------------------------------------------------------------
__global__ __launch_bounds__(256) void prep(
    const float* __restrict__ imgs, const float* __restrict__ feats,
    const float* __restrict__ W1, const float* __restrict__ b1,
    const float* __restrict__ W2, const float* __restrict__ b2,
    uint2* __restrict__ imgsP, uint4* __restrict__ featsP,
    unsigned int* __restrict__ Bfrag, float* __restrict__ bw)
{
    const int bidx = blockIdx.x;
    const int t = threadIdx.x;
    if (bidx < 1280) {
        // ---- images: 4 consecutive pixels per thread, u8 quantize ----
        int gid = bidx * 256 + t;               // 327,680
        int v   = gid >> 16;                    // 65536 pixel-quads per view
        int px  = (gid & 65535) * 4;
        const float* base = imgs + (size_t)v * 6 * IMG_HW + px;
        float4 pl[6];
        #pragma unroll
        for (int p = 0; p < 6; p++)
            pl[p] = *(const float4*)(base + (size_t)p * IMG_HW);
        uint2 o[4];
        #pragma unroll
        for (int i = 0; i < 4; i++) {
            unsigned int c[6];
            #pragma unroll
            for (int p = 0; p < 6; p++)
                c[p] = (unsigned int)fminf(((const float*)&pl[p])[i] * 255.f + 0.5f, 255.f);
            o[i].x = c[0] | (c[1] << 8) | (c[2] << 16);
            o[i].y = c[3] | (c[4] << 8) | (c[5] << 16);
        }
        uint4* dst = (uint4*)(imgsP + (size_t)v * IMG_HW + px);
        dst[0] = make_uint4(o[0].x, o[0].y, o[1].x, o[1].y);
        dst[1] = make_uint4(o[2].x, o[2].y, o[3].x, o[3].y);
    } else if (bidx < 2560) {
        // ---- features via LDS tile; float4 global loads; bf16 output ----
        __shared__ __align__(16) unsigned short tile[64][68];   // 68: 8B-aligned rows, bank spread
        const int pixbase = (bidx - 1280) * 64;
        const int v   = pixbase >> 14;
        const int rem = pixbase & 16383;
        {
            #pragma unroll
            for (int it = 0; it < 4; it++) {
                int idx   = it * 256 + t;        // [0,1024) float4 units
                int plane = idx >> 4;            // 64 planes (= b*32+ch)
                int px4   = (idx & 15) * 4;      // 4 px per load
                float4 f = *(const float4*)(feats + ((size_t)v * 64 + plane) * FT_HW + rem + px4);
                ushort4 o;
                o.x = (unsigned short)f2bf(f.x);
                o.y = (unsigned short)f2bf(f.y);
                o.z = (unsigned short)f2bf(f.z);
                o.w = (unsigned short)f2bf(f.w);
                *(ushort4*)&tile[plane][px4] = o;
            }
        }
        __syncthreads();
        {
            const int q = t & 7;
            #pragma unroll
            for (int it = 0; it < 2; it++) {
                int p = it * 32 + (t >> 3);
                uint4 o;
                o.x = (unsigned)tile[q * 8 + 0][p] | ((unsigned)tile[q * 8 + 1][p] << 16);
                o.y = (unsigned)tile[q * 8 + 2][p] | ((unsigned)tile[q * 8 + 3][p] << 16);
                o.z = (unsigned)tile[q * 8 + 4][p] | ((unsigned)tile[q * 8 + 5][p] << 16);
                o.w = (unsigned)tile[q * 8 + 6][p] | ((unsigned)tile[q * 8 + 7][p] << 16);
                featsP[(size_t)(pixbase + p) * 8 + q] = o;
            }
        }
    } else {
        // ---- W1 fragment image (mapk-permuted, bf16 pairs) ----
        int e = (bidx - 2560) * 256 + t;        // [0, 12288)
        int ju = e & 3;
        int nn = (e >> 2) & 255;
        int o  = e >> 10;
        int k0 = o * 8 + ju * 2;
        int i0 = mapk(k0), i1 = mapk(k0 + 1);
        float f0 = (i0 >= 0) ? W1[i0 * 256 + nn] : 0.f;
        float f1 = (i1 >= 0) ? W1[i1 * 256 + nn] : 0.f;
        Bfrag[e] = pk(f0, f1);
        if (e < 256)       bw[e] = b1[e];
        else if (e < 512)  bw[e] = W2[e - 256];
        else if (e == 512) bw[e] = b2[0];
    }
}

// ---------------------------------------------------------------------------
// Kernel 2: FUSED gather + MLP, 8-threads-per-bin, VALU-ISSUE-BOUND fixES.
// r9 counters: VALUBusy 65%, achieved waves saturated ~12/CU regardless of
// static caps (occupancy lever exhausted) -> cut the per-wave VALU stream:
//  * IMAGE CORNER SPREAD: corner k == lane's q (4 corners <-> 4 q-lanes).
//    Each lane does ONE corner (weight/mask/load/decode ~25 ops vs 4x serial
//    ~120 under exec-mask where 3/4 lanes idle-issue), then 2-step shfl_xor
//    butterfly over q bits (DS pipe, off the VALU) reduces corners. Also
//    4 VMEM instrs -> 1 per view.
//  * PACKED F32 feature blend: (ch even, ch odd) pairs as float2 -> LLVM
//    emits v_pk_fma_f32/v_pk_mul_f32 (VOP3P), halving blend+accum issue.
// CORRECTNESS (r6): separable validity masks + clamped int coords exactly
// match reference corner(); NaN/inf coords -> weight 0 via select.
// NUMERICS (r7): featsP bf16 (full f32 exponent range).
// VGPR (r2-r4, m69): state < 64 VGPRs, (256,4); never clamp below natural.
// A exchange INTRA-WAVE via LDS (no barrier); B staged in four 12KB quarters
// over the A region (15.4KB total LDS).
// mfma: A[m=lane&15][k=quad*8+j], B[k][n=lane&15], C: col=lane&15,
// row=quad*4+reg  [verified layouts, learn_hip m89]
// ---------------------------------------------------------------------------
#define AROW 13   // uint4s per LDS A-row (12 data + 1 pad for bank spread)

__global__ __launch_bounds__(256, 4) void fused_gather_mlp(
    const uint2* __restrict__ imgsP,            // [V][512][512] u8x8
    const unsigned short* __restrict__ featsP,  // [V][128][128][2][32] bf16
    const float* __restrict__ grid,             // [V][NB][2]
    const float* __restrict__ points,           // [NB][3]
    const unsigned int*   __restrict__ Bfrag,   // [12288] prebuilt fragments
    const float*          __restrict__ bw,      // b1(256) | W2(256) | b2(1)
    float* __restrict__ out)                    // [256000] = [B][NB]
{
    __shared__ unsigned int Lds[3328];          // 13.3 KB: A-tile (64x13 uint4); B-quarters (768 uint4 = 12KB) reuse it
    __shared__ float b1s[HID];
    __shared__ float W2s[HID];

    const int tid = threadIdx.x;
    b1s[tid] = bw[tid];
    W2s[tid] = bw[256 + tid];
    const float b2v = bw[512];

    // ================= gather phase =================
    const int n = blockIdx.x * 32 + (tid >> 3);
    const int b = (tid >> 2) & 1;
    const int q = tid & 3;
    const int qxi = q & 1;             // my image corner: x side
    const int qyi = q >> 1;            //                  y side
    const float qxf = (float)qxi;
    const float qyf = (float)qyi;

    f32x2 sum2[4], ssq2[4];
    #pragma unroll
    for (int d = 0; d < 4; d++) { sum2[d] = (f32x2){0.f, 0.f}; ssq2[d] = (f32x2){0.f, 0.f}; }
    float si0 = 0.f, si1 = 0.f, si2 = 0.f;      // 255-scaled img sums (valid in q0)
    float qi0 = 0.f, qi1 = 0.f, qi2 = 0.f;
    float p0 = 0.f, p1 = 0.f, p2 = 0.f;         // pts (q3)
    if (q == 3) {
        p0 = points[n * 3 + 0];
        p1 = points[n * 3 + 1];
        p2 = points[n * 3 + 2];
    }

    const uint4* fbase = (const uint4*)featsP + (size_t)b * 4 + q;  // +pixel*8 later

    #pragma unroll
    for (int v = 0; v < NVIEW; v++) {
        const float2 g = ((const float2*)grid)[v * NB + n];
        const float gx = g.x, gy = g.y;

        // ---- image sample: ONE corner per q-lane, shfl_xor reduce ----
        {
            float ix = (gx + 1.f) * 0.5f * 511.f;
            float iy = (gy + 1.f) * 0.5f * 511.f;
            float x0f = floorf(ix), y0f = floorf(iy);
            float wx1 = ix - x0f, wx0 = 1.f - wx1;
            float wy1 = iy - y0f, wy0 = 1.f - wy1;
            // my corner's weight + validity (matches reference corner())
            float wx = qxi ? wx1 : wx0;
            float wy = qyi ? wy1 : wy0;
            bool okx = qxi ? (x0f >= -1.f && x0f <= 510.f) : (x0f >= 0.f && x0f <= 511.f);
            bool oky = qyi ? (y0f >= -1.f && y0f <= 510.f) : (y0f >= 0.f && y0f <= 511.f);
            float wk = (okx && oky) ? wx * wy : 0.f;
            int xi = (int)fminf(fmaxf(x0f + qxf, 0.f), 511.f);
            int yi = (int)fminf(fmaxf(y0f + qyf, 0.f), 511.f);
            uint2 iv = imgsP[(size_t)v * IMG_HW + yi * 512 + xi];
            unsigned sel = b ? iv.y : iv.x;
            float c0 = wk * (float)(sel & 255u);
            float c1 = wk * (float)((sel >> 8) & 255u);
            float c2 = wk * (float)((sel >> 16) & 255u);
            // butterfly over q bits (lanes ^1, ^2): every lane gets the corner sum
            c0 += __shfl_xor(c0, 1); c1 += __shfl_xor(c1, 1); c2 += __shfl_xor(c2, 1);
            c0 += __shfl_xor(c0, 2); c1 += __shfl_xor(c1, 2); c2 += __shfl_xor(c2, 2);
            si0 += c0; qi0 += c0 * c0;
            si1 += c1; qi1 += c1 * c1;
            si2 += c2; qi2 += c2 * c2;
        }

        // ---- feature sample: 4 masked corner uint4 loads, packed-f32 blend ----
        {
            float ix = (gx + 1.f) * 0.5f * 127.f;
            float iy = (gy + 1.f) * 0.5f * 127.f;
            float x0f = floorf(ix), y0f = floorf(iy);
            float wx1 = ix - x0f, wx0 = 1.f - wx1;
            float wy1 = iy - y0f, wy0 = 1.f - wy1;
            wx0 = (x0f >= 0.f && x0f <= 127.f) ? wx0 : 0.f;
            wx1 = (x0f >= -1.f && x0f <= 126.f) ? wx1 : 0.f;
            wy0 = (y0f >= 0.f && y0f <= 127.f) ? wy0 : 0.f;
            wy1 = (y0f >= -1.f && y0f <= 126.f) ? wy1 : 0.f;
            float w00 = wx0 * wy0, w01 = wx1 * wy0, w10 = wx0 * wy1, w11 = wx1 * wy1;
            int xi0 = (int)fminf(fmaxf(x0f,       0.f), 127.f);
            int xi1 = (int)fminf(fmaxf(x0f + 1.f, 0.f), 127.f);
            int r0  = (int)fminf(fmaxf(y0f,       0.f), 127.f) * 128;
            int r1  = (int)fminf(fmaxf(y0f + 1.f, 0.f), 127.f) * 128;
            const uint4* fb = fbase + (size_t)v * (FT_HW * 8);
            uint4 c00 = fb[(size_t)(r0 + xi0) * 8];
            uint4 c01 = fb[(size_t)(r0 + xi1) * 8];
            uint4 c10 = fb[(size_t)(r1 + xi0) * 8];
            uint4 c11 = fb[(size_t)(r1 + xi1) * 8];
            const unsigned int* u00 = (const unsigned int*)&c00;
            const unsigned int* u01 = (const unsigned int*)&c01;
            const unsigned int* u10 = (const unsigned int*)&c10;
            const unsigned int* u11 = (const unsigned int*)&c11;
            #pragma unroll
            for (int d = 0; d < 4; d++) {
                f32x2 a00 = {b2f_lo(u00[d]), b2f_hi(u00[d])};
                f32x2 a01 = {b2f_lo(u01[d]), b2f_hi(u01[d])};
                f32x2 a10 = {b2f_lo(u10[d]), b2f_hi(u10[d])};
                f32x2 a11 = {b2f_lo(u11[d]), b2f_hi(u11[d])};
                f32x2 val = w00 * a00 + w01 * a01 + w10 * a10 + w11 * a11;
                sum2[d] += val;
                ssq2[d] += val * val;
            }
        }
    }

    // finalize mean / exp(-var)  (img sums rescaled from 255-space here)
    float sumf[8], ssqf[8];
    #pragma unroll
    for (int d = 0; d < 4; d++) {
        sumf[2 * d]     = sum2[d][0];
        sumf[2 * d + 1] = sum2[d][1];
        ssqf[2 * d]     = ssq2[d][0];
        ssqf[2 * d + 1] = ssq2[d][1];
    }
    #pragma unroll
    for (int c = 0; c < 8; c++) {
        float m = sumf[c] * 0.2f;
        float qq = ssqf[c] * 0.2f - m * m;
        sumf[c] = m;
        ssqf[c] = __expf(-qq);
    }
    const float s1 = 0.2f * (1.f / 255.f);
    const float s2 = 0.2f * (1.f / 65025.f);
    float mi0 = si0 * s1, mi1 = si1 * s1, mi2 = si2 * s1;
    float ei0 = __expf(-(qi0 * s2 - mi0 * mi0));
    float ei1 = __expf(-(qi1 * s2 - mi1 * mi1));
    float ei2 = __expf(-(qi2 * s2 - mi2 * mi2));

    // pack my 24 shorts (= 12 uints = 3 uint4) per the quarter-row layout
    unsigned int u[12];
    if (q == 0) {
        u[0] = pk(mi0, mi1);
        u[1] = pk(mi2, ei0);
        u[2] = pk(ei1, ei2);
        #pragma unroll
        for (int j = 0; j < 4; j++) u[3 + j] = pk(sumf[2 * j], sumf[2 * j + 1]);
        #pragma unroll
        for (int j = 0; j < 4; j++) u[7 + j] = pk(ssqf[2 * j], ssqf[2 * j + 1]);
        u[11] = 0u;
    } else {
        #pragma unroll
        for (int j = 0; j < 4; j++) u[j]     = pk(sumf[2 * j], sumf[2 * j + 1]);
        #pragma unroll
        for (int j = 0; j < 4; j++) u[4 + j] = pk(ssqf[2 * j], ssqf[2 * j + 1]);
        u[8] = 0u; u[9] = 0u; u[10] = 0u; u[11] = 0u;
        if (q == 3) { u[8] = pk(p0, p1); u[9] = pk(p2, 0.f); }
    }

    // ---- intra-wave A exchange through Lds (NO barrier needed) ----
    // row = tid>>2 (rows 16w..16w+15 belong to wave w); thread q writes
    // granules 3q..3q+2 (shorts 24q..24q+24).
    uint4* As4 = (uint4*)Lds;
    {
        uint4* arow = &As4[(tid >> 2) * AROW + q * 3];
        #pragma unroll
        for (int i = 0; i < 3; i++)
            arow[i] = make_uint4(u[4 * i], u[4 * i + 1], u[4 * i + 2], u[4 * i + 3]);
    }

    const int w    = tid >> 6;
    const int lane = tid & 63;
    const int col  = lane & 15;
    const int quad = lane >> 4;
    const long rowbase = (long)blockIdx.x * 64 + w * 16;

    // pull A fragments into registers (lgkmcnt-ordered vs the writes above)
    // MFMA s consumes k [32s,32s+32); lane quad reads granule 4s+quad.
    short8 af[3];
    #pragma unroll
    for (int s = 0; s < 3; s++)
        af[s] = *(const short8*)&As4[(w * 16 + col) * AROW + s * 4 + quad];

    __syncthreads();   // (1) all waves done with the A region

    // ========== GEMM phase: four 12KB B-quarters over the A buffer ==========
    // Bfrag uint4 idx of (s, t_global, quad, col) = s*1024 + quad*256 + t_global*16 + col
    // Quarter qb holds t_global in [4qb, 4qb+4); LDS uint4 idx:
    //   g = s*256 + quad*64 + tt*16 + col   (tt in [0,4))
    //   src = (g>>8)*1024 + ((g>>6)&3)*256 + qb*64 + (g&63)
    float pm[4] = {0.f, 0.f, 0.f, 0.f};
    #pragma unroll
    for (int qb = 0; qb < 4; qb++) {
        {
            const uint4* src = (const uint4*)Bfrag;
            uint4* dst = (uint4*)Lds;
            #pragma unroll
            for (int i = 0; i < 3; i++) {
                int g = i * 256 + tid;                      // [0,768)
                dst[g] = src[(g >> 8) * 1024 + ((g >> 6) & 3) * 256 + qb * 64 + (g & 63)];
            }
        }
        __syncthreads();   // B-quarter visible (qb=0: also covers b1s/W2s)

        f32x4 acc[4];
        #pragma unroll
        for (int tt = 0; tt < 4; tt++)
            acc[tt] = (f32x4){0.f, 0.f, 0.f, 0.f};

        const unsigned int* bp = Lds + quad * 256 + col * 4;
        #pragma unroll
        for (int s = 0; s < 3; s++) {
            #pragma unroll
            for (int tt = 0; tt < 4; tt++) {
                short8 bf = *(const short8*)(bp + s * 1024 + tt * 64);
                acc[tt] = __builtin_amdgcn_mfma_f32_16x16x32_bf16(af[s], bf, acc[tt], 0, 0, 0);
            }
        }

        // epilogue partials: +b1, relu, dot W2 over this quarter's 64 cols
        #pragma unroll
        for (int tt = 0; tt < 4; tt++) {
            int j = (qb * 4 + tt) * 16 + col;
            float b1v = b1s[j];
            float w2v = W2s[j];
            #pragma unroll
            for (int r = 0; r < 4; r++) {
                float hh = fmaxf(acc[tt][r] + b1v, 0.f);
                pm[r] += hh * w2v;
            }
        }
        if (qb < 3) __syncthreads();   // all waves done reading before restage
    }

    // reduce over the 16 cols (lanes quad*16 .. quad*16+15)
    #pragma unroll
    for (int r = 0; r < 4; r++) {
        float p = pm[r];
        p += __shfl_xor(p, 1);
        p += __shfl_xor(p, 2);
        p += __shfl_xor(p, 4);
        p += __shfl_xor(p, 8);
        pm[r] = p;
    }

    if (col == 0) {
        #pragma unroll
        for (int r = 0; r < 4; r++) {
            float x  = pm[r] + b2v;
            float sp = fmaxf(x, 0.f) + log1pf(expf(-fabsf(x)));  // softplus
            float alpha = -expm1f(-sp);                          // 1 - exp(-sp)
            long row = rowbase + quad * 4 + r;                   // = 2n + b
            out[(row & 1) * (long)NB + (row >> 1)] = alpha;
        }
    }
}

extern "C" void kernel_launch(void* const* d_in, const int* in_sizes, int n_in,
                              void* d_out, int out_size, void* d_ws, size_t ws_size,
                              hipStream_t stream) {
    const float* imgs   = (const float*)d_in[0];
    const float* feats  = (const float*)d_in[1];
    const float* grid   = (const float*)d_in[2];
    const float* points = (const float*)d_in[3];
    const float* W1     = (const float*)d_in[4];
    const float* b1     = (const float*)d_in[5];
    const float* W2     = (const float*)d_in[6];
    const float* b2     = (const float*)d_in[7];
    float* out = (float*)d_out;

    // workspace: imgsP(u8) 10.49MB | featsP(bf16) 10.49MB | Bfrag 48KB | bw 2.05KB
    uint2*          imgsP  = (uint2*)d_ws;
    unsigned short* featsP = (unsigned short*)(imgsP + (size_t)NVIEW * IMG_HW);
    unsigned int*   Bfrag  = (unsigned int*)(featsP + (size_t)NVIEW * FT_HW * 64);
    float*          bwbuf  = (float*)(Bfrag + 12288);

    prep<<<dim3(2608), dim3(256), 0, stream>>>(
        imgs, feats, W1, b1, W2, b2,
        imgsP, (uint4*)featsP, Bfrag, bwbuf);
    fused_gather_mlp<<<dim3(4000), dim3(256), 0, stream>>>(
        imgsP, featsP, grid, points, Bfrag, bwbuf, out);
}

// Round 11
// 173.320 us; speedup vs baseline: 1.0234x; 1.0234x over previous
//
#include <hip/hip_runtime.h>

// Problem constants (from reference; all fp32 I/O)
#define NVIEW 5
#define NB    128000          // NBINS = 80*80*20
#define CF    32
#define HID   256
#define KA    96              // padded K for the MLP GEMM
#define IMG_HW 262144         // 512*512
#define FT_HW  16384          // 128*128

typedef __attribute__((ext_vector_type(8))) short short8;     // 8 bf16 (4 VGPRs)
typedef __attribute__((ext_vector_type(4))) float f32x4;      // MFMA accumulator
typedef __attribute__((ext_vector_type(2))) float f32x2;      // packed fp32 (v_pk_*)

__device__ __forceinline__ unsigned int f2bf(float f) {
    unsigned int u = __float_as_uint(f);
    return (u + 0x7fffu + ((u >> 16) & 1u)) >> 16;   // RTNE, low 16 bits
}
__device__ __forceinline__ unsigned int pk(float a, float b) {
    return f2bf(a) | (f2bf(b) << 16);
}
__device__ __forceinline__ float b2f_lo(unsigned int u) { return __uint_as_float(u << 16); }
__device__ __forceinline__ float b2f_hi(unsigned int u) { return __uint_as_float(u & 0xffff0000u); }

// A-row layout, QUARTER-ROW ownership (96 shorts per row = bin 2n+b, built by
// 4 threads q=0..3; thread q owns shorts [24q, 24q+24) = granules 3q..3q+2):
//  q0: mi(3) vi(3) mf ch0..7 (8) vf ch0..7 (8) pad(2)
//  q1: mf ch8..15 (8)  vf ch8..15 (8)  pad(8)
//  q2: mf ch16..23 (8) vf ch16..23 (8) pad(8)
//  q3: mf ch24..31 (8) vf ch24..31 (8) pts(3) pad(5)
// W1 input order i: 0-2 pts | 3-5 img_mean | 6-37 feat_mean | 38-40 img_var
// | 41-72 feat_var.  mapk: A-row k -> i, -1 = zero pad.
__device__ __forceinline__ int mapk(int k) {
    if (k < 3)  return k + 3;      // img mean
    if (k < 6)  return k + 35;     // img var (38..40)
    if (k < 14) return k;          // feat mean 0..7  (6..13)
    if (k < 22) return k + 27;     // feat var 0..7   (41..48)
    if (k < 24) return -1;
    if (k < 32) return k - 10;     // feat mean 8..15 (14..21)
    if (k < 40) return k + 17;     // feat var 8..15  (49..56)
    if (k < 48) return -1;
    if (k < 56) return k - 26;     // feat mean 16..23 (22..29)
    if (k < 64) return k + 1;      // feat var 16..23  (57..64)
    if (k < 72) return -1;
    if (k < 80) return k - 42;     // feat mean 24..31 (30..37)
    if (k < 88) return k - 15;     // feat var 24..31  (65..72)
    if (k < 91) return k - 88;     // pts
    return -1;
}

// ---------------------------------------------------------------------------
// Kernel 1: ALL preprocessing in one launch (blockIdx-range split).
//  [0,1280):    repack imgs (4 px/thread) -> [V][512][512][8] uint8 fixed-pt
//  [1280,2560): repack feats -> [V][128][128][2][32] bf16 (LDS tile, float4 loads)
//  [2560,2608): build W1 B-fragment image + b1|W2|b2 staging
// NUMERICS LESSON (r6/r7): harness re-poisons inputs; feats can carry
// magnitudes far outside N(0,1) (f16 storage -> 3.5e-2 error / inf risk).
// bf16 keeps f32's exponent range -> always safe.
// ---------------------------------------------------------------------------
__global__ __launch_bounds__(256) void prep(
    const float* __restrict__ imgs, const float* __restrict__ feats,
    const float* __restrict__ W1, const float* __restrict__ b1,
    const float* __restrict__ W2, const float* __restrict__ b2,
    uint2* __restrict__ imgsP, uint4* __restrict__ featsP,
    unsigned int* __restrict__ Bfrag, float* __restrict__ bw)
{
    const int bidx = blockIdx.x;
    const int t = threadIdx.x;
    if (bidx < 1280) {
        // ---- images: 4 consecutive pixels per thread, u8 quantize ----
        int gid = bidx * 256 + t;               // 327,680
        int v   = gid >> 16;                    // 65536 pixel-quads per view
        int px  = (gid & 65535) * 4;
        const float* base = imgs + (size_t)v * 6 * IMG_HW + px;
        float4 pl[6];
        #pragma unroll
        for (int p = 0; p < 6; p++)
            pl[p] = *(const float4*)(base + (size_t)p * IMG_HW);
        uint2 o[4];
        #pragma unroll
        for (int i = 0; i < 4; i++) {
            unsigned int c[6];
            #pragma unroll
            for (int p = 0; p < 6; p++)
                c[p] = (unsigned int)fminf(((const float*)&pl[p])[i] * 255.f + 0.5f, 255.f);
            o[i].x = c[0] | (c[1] << 8) | (c[2] << 16);
            o[i].y = c[3] | (c[4] << 8) | (c[5] << 16);
        }
        uint4* dst = (uint4*)(imgsP + (size_t)v * IMG_HW + px);
        dst[0] = make_uint4(o[0].x, o[0].y, o[1].x, o[1].y);
        dst[1] = make_uint4(o[2].x, o[2].y, o[3].x, o[3].y);
    } else if (bidx < 2560) {
        // ---- features via LDS tile; float4 global loads; bf16 output ----
        __shared__ __align__(16) unsigned short tile[64][68];   // 68: 8B-aligned rows, bank spread
        const int pixbase = (bidx - 1280) * 64;
        const int v   = pixbase >> 14;
        const int rem = pixbase & 16383;
        {
            #pragma unroll
            for (int it = 0; it < 4; it++) {
                int idx   = it * 256 + t;        // [0,1024) float4 units
                int plane = idx >> 4;            // 64 planes (= b*32+ch)
                int px4   = (idx & 15) * 4;      // 4 px per load
                float4 f = *(const float4*)(feats + ((size_t)v * 64 + plane) * FT_HW + rem + px4);
                ushort4 o;
                o.x = (unsigned short)f2bf(f.x);
                o.y = (unsigned short)f2bf(f.y);
                o.z = (unsigned short)f2bf(f.z);
                o.w = (unsigned short)f2bf(f.w);
                *(ushort4*)&tile[plane][px4] = o;
            }
        }
        __syncthreads();
        {
            const int q = t & 7;
            #pragma unroll
            for (int it = 0; it < 2; it++) {
                int p = it * 32 + (t >> 3);
                uint4 o;
                o.x = (unsigned)tile[q * 8 + 0][p] | ((unsigned)tile[q * 8 + 1][p] << 16);
                o.y = (unsigned)tile[q * 8 + 2][p] | ((unsigned)tile[q * 8 + 3][p] << 16);
                o.z = (unsigned)tile[q * 8 + 4][p] | ((unsigned)tile[q * 8 + 5][p] << 16);
                o.w = (unsigned)tile[q * 8 + 6][p] | ((unsigned)tile[q * 8 + 7][p] << 16);
                featsP[(size_t)(pixbase + p) * 8 + q] = o;
            }
        }
    } else {
        // ---- W1 fragment image (mapk-permuted, bf16 pairs) ----
        int e = (bidx - 2560) * 256 + t;        // [0, 12288)
        int ju = e & 3;
        int nn = (e >> 2) & 255;
        int o  = e >> 10;
        int k0 = o * 8 + ju * 2;
        int i0 = mapk(k0), i1 = mapk(k0 + 1);
        float f0 = (i0 >= 0) ? W1[i0 * 256 + nn] : 0.f;
        float f1 = (i1 >= 0) ? W1[i1 * 256 + nn] : 0.f;
        Bfrag[e] = pk(f0, f1);
        if (e < 256)       bw[e] = b1[e];
        else if (e < 512)  bw[e] = W2[e - 256];
        else if (e == 512) bw[e] = b2[0];
    }
}

// ---------------------------------------------------------------------------
// Kernel 2: FUSED gather + MLP, 8-threads-per-bin, FULL-ILP GATHER.
// r10 counters: dur flat at ~83us across 4 rounds with VALUBusy 58-65% and
// occupancy 36-44% -> latency-bound on the per-wave SERIAL view chain
// (L~500cy per view's scattered loads, P~100cy blend; busy model
// waves*P/(P+L-P) ~ 0.57 matches measured 58%). At 48 VGPRs the compiler
// can't keep multiple views' corner data in flight. Fix: spend registers
// on ILP -> (256,2) cap 128:
//  * hoist all 5 grid loads;
//  * issue ALL 5 image corner loads upfront (10 VGPRs data);
//  * double-buffer feature corner-sets (cA/cB, 32 VGPRs): issue view v+2
//    right after consuming view v. Explicit unrolled schedule, constant
//    indexing only (runtime-indexed arrays -> scratch, rule #20 / r2 lesson).
// Math/masks byte-identical to r10 (passed, absmax 0.0078).
// CORRECTNESS (r6): separable validity masks + clamped int coords match
// reference corner(); NaN/inf coords -> weight 0. NUMERICS (r7): featsP bf16.
// A exchange INTRA-WAVE via LDS (no barrier); B staged in four 12KB quarters
// over the A region (15.4KB LDS).
// mfma: A[m=lane&15][k=quad*8+j], B[k][n=lane&15], C: col=lane&15,
// row=quad*4+reg  [verified layouts, learn_hip m89]
// ---------------------------------------------------------------------------
#define AROW 13   // uint4s per LDS A-row (12 data + 1 pad for bank spread)

__global__ __launch_bounds__(256, 2) void fused_gather_mlp(
    const uint2* __restrict__ imgsP,            // [V][512][512] u8x8
    const unsigned short* __restrict__ featsP,  // [V][128][128][2][32] bf16
    const float* __restrict__ grid,             // [V][NB][2]
    const float* __restrict__ points,           // [NB][3]
    const unsigned int*   __restrict__ Bfrag,   // [12288] prebuilt fragments
    const float*          __restrict__ bw,      // b1(256) | W2(256) | b2(1)
    float* __restrict__ out)                    // [256000] = [B][NB]
{
    __shared__ unsigned int Lds[3328];          // 13.3 KB: A-tile (64x13 uint4); B-quarters (768 uint4 = 12KB) reuse it
    __shared__ float b1s[HID];
    __shared__ float W2s[HID];

    const int tid = threadIdx.x;
    b1s[tid] = bw[tid];
    W2s[tid] = bw[256 + tid];
    const float b2v = bw[512];

    // ================= gather phase =================
    const int n = blockIdx.x * 32 + (tid >> 3);
    const int b = (tid >> 2) & 1;
    const int q = tid & 3;
    const int qxi = q & 1;             // my image corner: x side
    const int qyi = q >> 1;            //                  y side
    const float qxf = (float)qxi;
    const float qyf = (float)qyi;

    f32x2 sum2[4], ssq2[4];
    #pragma unroll
    for (int d = 0; d < 4; d++) { sum2[d] = (f32x2){0.f, 0.f}; ssq2[d] = (f32x2){0.f, 0.f}; }
    float si0 = 0.f, si1 = 0.f, si2 = 0.f;      // 255-scaled img sums
    float qi0 = 0.f, qi1 = 0.f, qi2 = 0.f;
    float p0 = 0.f, p1 = 0.f, p2 = 0.f;         // pts (q3)
    if (q == 3) {
        p0 = points[n * 3 + 0];
        p1 = points[n * 3 + 1];
        p2 = points[n * 3 + 2];
    }

    const uint4* fbase = (const uint4*)featsP + (size_t)b * 4 + q;  // +pixel*8 later

    // ---- hoist all 5 grid loads (independent, issued together) ----
    float2 g[NVIEW];
    #pragma unroll
    for (int v = 0; v < NVIEW; v++)
        g[v] = ((const float2*)grid)[v * NB + n];

    // ---- issue ALL 5 image corner loads upfront (one corner per q-lane) ----
    uint2 ivv[NVIEW];
    float wki[NVIEW];
    #pragma unroll
    for (int v = 0; v < NVIEW; v++) {
        float ix = (g[v].x + 1.f) * 0.5f * 511.f;
        float iy = (g[v].y + 1.f) * 0.5f * 511.f;
        float x0f = floorf(ix), y0f = floorf(iy);
        float wx1 = ix - x0f, wx0 = 1.f - wx1;
        float wy1 = iy - y0f, wy0 = 1.f - wy1;
        float wx = qxi ? wx1 : wx0;
        float wy = qyi ? wy1 : wy0;
        bool okx = qxi ? (x0f >= -1.f && x0f <= 510.f) : (x0f >= 0.f && x0f <= 511.f);
        bool oky = qyi ? (y0f >= -1.f && y0f <= 510.f) : (y0f >= 0.f && y0f <= 511.f);
        wki[v] = (okx && oky) ? wx * wy : 0.f;
        int xi = (int)fminf(fmaxf(x0f + qxf, 0.f), 511.f);
        int yi = (int)fminf(fmaxf(y0f + qyf, 0.f), 511.f);
        ivv[v] = imgsP[(size_t)v * IMG_HW + yi * 512 + xi];
    }

    // ---- feature sampler helpers (byte-identical math to r10) ----
    auto featIssue = [&](float2 gg, const uint4* fb, uint4 (&c)[4], float (&wf)[4]) {
        float ix = (gg.x + 1.f) * 0.5f * 127.f;
        float iy = (gg.y + 1.f) * 0.5f * 127.f;
        float x0f = floorf(ix), y0f = floorf(iy);
        float wx1 = ix - x0f, wx0 = 1.f - wx1;
        float wy1 = iy - y0f, wy0 = 1.f - wy1;
        wx0 = (x0f >= 0.f && x0f <= 127.f) ? wx0 : 0.f;
        wx1 = (x0f >= -1.f && x0f <= 126.f) ? wx1 : 0.f;
        wy0 = (y0f >= 0.f && y0f <= 127.f) ? wy0 : 0.f;
        wy1 = (y0f >= -1.f && y0f <= 126.f) ? wy1 : 0.f;
        wf[0] = wx0 * wy0; wf[1] = wx1 * wy0; wf[2] = wx0 * wy1; wf[3] = wx1 * wy1;
        int xi0 = (int)fminf(fmaxf(x0f,       0.f), 127.f);
        int xi1 = (int)fminf(fmaxf(x0f + 1.f, 0.f), 127.f);
        int r0  = (int)fminf(fmaxf(y0f,       0.f), 127.f) * 128;
        int r1  = (int)fminf(fmaxf(y0f + 1.f, 0.f), 127.f) * 128;
        c[0] = fb[(size_t)(r0 + xi0) * 8];
        c[1] = fb[(size_t)(r0 + xi1) * 8];
        c[2] = fb[(size_t)(r1 + xi0) * 8];
        c[3] = fb[(size_t)(r1 + xi1) * 8];
    };
    auto featConsume = [&](uint4 (&c)[4], float (&wf)[4]) {
        const unsigned int* u00 = (const unsigned int*)&c[0];
        const unsigned int* u01 = (const unsigned int*)&c[1];
        const unsigned int* u10 = (const unsigned int*)&c[2];
        const unsigned int* u11 = (const unsigned int*)&c[3];
        #pragma unroll
        for (int d = 0; d < 4; d++) {
            f32x2 a00 = {b2f_lo(u00[d]), b2f_hi(u00[d])};
            f32x2 a01 = {b2f_lo(u01[d]), b2f_hi(u01[d])};
            f32x2 a10 = {b2f_lo(u10[d]), b2f_hi(u10[d])};
            f32x2 a11 = {b2f_lo(u11[d]), b2f_hi(u11[d])};
            f32x2 val = wf[0] * a00 + wf[1] * a01 + wf[2] * a10 + wf[3] * a11;
            sum2[d] += val;
            ssq2[d] += val * val;
        }
    };
    auto imgConsume = [&](uint2 iv, float wk) {
        unsigned sel = b ? iv.y : iv.x;
        float c0 = wk * (float)(sel & 255u);
        float c1 = wk * (float)((sel >> 8) & 255u);
        float c2 = wk * (float)((sel >> 16) & 255u);
        c0 += __shfl_xor(c0, 1); c1 += __shfl_xor(c1, 1); c2 += __shfl_xor(c2, 1);
        c0 += __shfl_xor(c0, 2); c1 += __shfl_xor(c1, 2); c2 += __shfl_xor(c2, 2);
        si0 += c0; qi0 += c0 * c0;
        si1 += c1; qi1 += c1 * c1;
        si2 += c2; qi2 += c2 * c2;
    };

    // ---- software-pipelined schedule: feat depth-2, img full-depth ----
    uint4 cA[4], cB[4];
    float wA[4], wB[4];
    const size_t VSTRIDE = (size_t)FT_HW * 8;
    featIssue(g[0], fbase + 0 * VSTRIDE, cA, wA);
    featIssue(g[1], fbase + 1 * VSTRIDE, cB, wB);
    featConsume(cA, wA); featIssue(g[2], fbase + 2 * VSTRIDE, cA, wA); imgConsume(ivv[0], wki[0]);
    featConsume(cB, wB); featIssue(g[3], fbase + 3 * VSTRIDE, cB, wB); imgConsume(ivv[1], wki[1]);
    featConsume(cA, wA); featIssue(g[4], fbase + 4 * VSTRIDE, cA, wA); imgConsume(ivv[2], wki[2]);
    featConsume(cB, wB); imgConsume(ivv[3], wki[3]);
    featConsume(cA, wA); imgConsume(ivv[4], wki[4]);

    // finalize mean / exp(-var)  (img sums rescaled from 255-space here)
    float sumf[8], ssqf[8];
    #pragma unroll
    for (int d = 0; d < 4; d++) {
        sumf[2 * d]     = sum2[d][0];
        sumf[2 * d + 1] = sum2[d][1];
        ssqf[2 * d]     = ssq2[d][0];
        ssqf[2 * d + 1] = ssq2[d][1];
    }
    #pragma unroll
    for (int c = 0; c < 8; c++) {
        float m = sumf[c] * 0.2f;
        float qq = ssqf[c] * 0.2f - m * m;
        sumf[c] = m;
        ssqf[c] = __expf(-qq);
    }
    const float s1 = 0.2f * (1.f / 255.f);
    const float s2 = 0.2f * (1.f / 65025.f);
    float mi0 = si0 * s1, mi1 = si1 * s1, mi2 = si2 * s1;
    float ei0 = __expf(-(qi0 * s2 - mi0 * mi0));
    float ei1 = __expf(-(qi1 * s2 - mi1 * mi1));
    float ei2 = __expf(-(qi2 * s2 - mi2 * mi2));

    // pack my 24 shorts (= 12 uints = 3 uint4) per the quarter-row layout
    unsigned int u[12];
    if (q == 0) {
        u[0] = pk(mi0, mi1);
        u[1] = pk(mi2, ei0);
        u[2] = pk(ei1, ei2);
        #pragma unroll
        for (int j = 0; j < 4; j++) u[3 + j] = pk(sumf[2 * j], sumf[2 * j + 1]);
        #pragma unroll
        for (int j = 0; j < 4; j++) u[7 + j] = pk(ssqf[2 * j], ssqf[2 * j + 1]);
        u[11] = 0u;
    } else {
        #pragma unroll
        for (int j = 0; j < 4; j++) u[j]     = pk(sumf[2 * j], sumf[2 * j + 1]);
        #pragma unroll
        for (int j = 0; j < 4; j++) u[4 + j] = pk(ssqf[2 * j], ssqf[2 * j + 1]);
        u[8] = 0u; u[9] = 0u; u[10] = 0u; u[11] = 0u;
        if (q == 3) { u[8] = pk(p0, p1); u[9] = pk(p2, 0.f); }
    }

    // ---- intra-wave A exchange through Lds (NO barrier needed) ----
    // row = tid>>2 (rows 16w..16w+15 belong to wave w); thread q writes
    // granules 3q..3q+2 (shorts 24q..24q+24).
    uint4* As4 = (uint4*)Lds;
    {
        uint4* arow = &As4[(tid >> 2) * AROW + q * 3];
        #pragma unroll
        for (int i = 0; i < 3; i++)
            arow[i] = make_uint4(u[4 * i], u[4 * i + 1], u[4 * i + 2], u[4 * i + 3]);
    }

    const int w    = tid >> 6;
    const int lane = tid & 63;
    const int col  = lane & 15;
    const int quad = lane >> 4;
    const long rowbase = (long)blockIdx.x * 64 + w * 16;

    // pull A fragments into registers (lgkmcnt-ordered vs the writes above)
    // MFMA s consumes k [32s,32s+32); lane quad reads granule 4s+quad.
    short8 af[3];
    #pragma unroll
    for (int s = 0; s < 3; s++)
        af[s] = *(const short8*)&As4[(w * 16 + col) * AROW + s * 4 + quad];

    __syncthreads();   // (1) all waves done with the A region

    // ========== GEMM phase: four 12KB B-quarters over the A buffer ==========
    // Bfrag uint4 idx of (s, t_global, quad, col) = s*1024 + quad*256 + t_global*16 + col
    // Quarter qb holds t_global in [4qb, 4qb+4); LDS uint4 idx:
    //   g = s*256 + quad*64 + tt*16 + col   (tt in [0,4))
    //   src = (g>>8)*1024 + ((g>>6)&3)*256 + qb*64 + (g&63)
    float pm[4] = {0.f, 0.f, 0.f, 0.f};
    #pragma unroll
    for (int qb = 0; qb < 4; qb++) {
        {
            const uint4* src = (const uint4*)Bfrag;
            uint4* dst = (uint4*)Lds;
            #pragma unroll
            for (int i = 0; i < 3; i++) {
                int gg = i * 256 + tid;                     // [0,768)
                dst[gg] = src[(gg >> 8) * 1024 + ((gg >> 6) & 3) * 256 + qb * 64 + (gg & 63)];
            }
        }
        __syncthreads();   // B-quarter visible (qb=0: also covers b1s/W2s)

        f32x4 acc[4];
        #pragma unroll
        for (int tt = 0; tt < 4; tt++)
            acc[tt] = (f32x4){0.f, 0.f, 0.f, 0.f};

        const unsigned int* bp = Lds + quad * 256 + col * 4;
        #pragma unroll
        for (int s = 0; s < 3; s++) {
            #pragma unroll
            for (int tt = 0; tt < 4; tt++) {
                short8 bf = *(const short8*)(bp + s * 1024 + tt * 64);
                acc[tt] = __builtin_amdgcn_mfma_f32_16x16x32_bf16(af[s], bf, acc[tt], 0, 0, 0);
            }
        }

        // epilogue partials: +b1, relu, dot W2 over this quarter's 64 cols
        #pragma unroll
        for (int tt = 0; tt < 4; tt++) {
            int j = (qb * 4 + tt) * 16 + col;
            float b1v = b1s[j];
            float w2v = W2s[j];
            #pragma unroll
            for (int r = 0; r < 4; r++) {
                float hh = fmaxf(acc[tt][r] + b1v, 0.f);
                pm[r] += hh * w2v;
            }
        }
        if (qb < 3) __syncthreads();   // all waves done reading before restage
    }

    // reduce over the 16 cols (lanes quad*16 .. quad*16+15)
    #pragma unroll
    for (int r = 0; r < 4; r++) {
        float p = pm[r];
        p += __shfl_xor(p, 1);
        p += __shfl_xor(p, 2);
        p += __shfl_xor(p, 4);
        p += __shfl_xor(p, 8);
        pm[r] = p;
    }

    if (col == 0) {
        #pragma unroll
        for (int r = 0; r < 4; r++) {
            float x  = pm[r] + b2v;
            float sp = fmaxf(x, 0.f) + log1pf(expf(-fabsf(x)));  // softplus
            float alpha = -expm1f(-sp);                          // 1 - exp(-sp)
            long row = rowbase + quad * 4 + r;                   // = 2n + b
            out[(row & 1) * (long)NB + (row >> 1)] = alpha;
        }
    }
}

extern "C" void kernel_launch(void* const* d_in, const int* in_sizes, int n_in,
                              void* d_out, int out_size, void* d_ws, size_t ws_size,
                              hipStream_t stream) {
    const float* imgs   = (const float*)d_in[0];
    const float* feats  = (const float*)d_in[1];
    const float* grid   = (const float*)d_in[2];
    const float* points = (const float*)d_in[3];
    const float* W1     = (const float*)d_in[4];
    const float* b1     = (const float*)d_in[5];
    const float* W2     = (const float*)d_in[6];
    const float* b2     = (const float*)d_in[7];
    float* out = (float*)d_out;

    // workspace: imgsP(u8) 10.49MB | featsP(bf16) 10.49MB | Bfrag 48KB | bw 2.05KB
    uint2*          imgsP  = (uint2*)d_ws;
    unsigned short* featsP = (unsigned short*)(imgsP + (size_t)NVIEW * IMG_HW);
    unsigned int*   Bfrag  = (unsigned int*)(featsP + (size_t)NVIEW * FT_HW * 64);
    float*          bwbuf  = (float*)(Bfrag + 12288);

    prep<<<dim3(2608), dim3(256), 0, stream>>>(
        imgs, feats, W1, b1, W2, b2,
        imgsP, (uint4*)featsP, Bfrag, bwbuf);
    fused_gather_mlp<<<dim3(4000), dim3(256), 0, stream>>>(
        imgsP, featsP, grid, points, Bfrag, bwbuf, out);
}